// Round 7
// baseline (1446.567 us; speedup 1.0000x reference)
//
#include <hip/hip_runtime.h>

// ---------------------------------------------------------------------------
// SNN over 3 graph levels.  Structure:
//   spmm(A, leaky(x)) @ T == A @ (leaky(x) @ T)   -> project first (15-wide)
//   mean_pool(s @ T3)    == (segsum(s) @ T3)/c    -> defer T3 to finalize
//   On-device CSR build per level (hist + scan + scatter), then 3 gather-SpMMs
//   with NO atomics.  batch[] is sorted -> pooling is contiguous-segment sum.
// Feature dim padded 15 -> 16 (64 B rows, one cache-line gather per edge).
// ---------------------------------------------------------------------------

#define CONV 15
#define PADW 16
#define OUTW 32
#define NG   64
#define PSPLIT 8   // blocks per graph in pooling

__device__ __forceinline__ float leaky(float v) {
    return v >= 0.f ? v : 0.01f * v;
}

// ---------------- CSR build ----------------

__global__ void hist_rows(const int* __restrict__ row, int* __restrict__ counts, int nnz) {
    int i = blockIdx.x * blockDim.x + threadIdx.x;
    if (i < nnz) atomicAdd(&counts[row[i]], 1);
}

// scan pass 1: per-block (1024 items) exclusive scan, block totals to bsum
__global__ void scan1(const int* __restrict__ counts, int* __restrict__ start,
                      int* __restrict__ bsum, int n) {
    __shared__ int s[256];
    int base = blockIdx.x * 1024 + threadIdx.x * 4;
    int v[4];
    int sum = 0;
#pragma unroll
    for (int k = 0; k < 4; ++k) {
        int idx = base + k;
        v[k] = (idx < n) ? counts[idx] : 0;
        sum += v[k];
    }
    s[threadIdx.x] = sum;
    __syncthreads();
    for (int off = 1; off < 256; off <<= 1) {
        int t = (threadIdx.x >= off) ? s[threadIdx.x - off] : 0;
        __syncthreads();
        s[threadIdx.x] += t;
        __syncthreads();
    }
    int run = (threadIdx.x > 0) ? s[threadIdx.x - 1] : 0;
    if (threadIdx.x == 255) bsum[blockIdx.x] = s[255];
#pragma unroll
    for (int k = 0; k < 4; ++k) {
        int idx = base + k;
        if (idx < n) start[idx] = run;
        run += v[k];
    }
}

// scan pass 2: single block exclusive-scans block sums (nb <= 512)
__global__ void scan2(int* __restrict__ bsum, int nb) {
    __shared__ int s[512];
    int t = threadIdx.x;
    s[t] = (t < nb) ? bsum[t] : 0;
    __syncthreads();
    for (int off = 1; off < 512; off <<= 1) {
        int v = (t >= off) ? s[t - off] : 0;
        __syncthreads();
        s[t] += v;
        __syncthreads();
    }
    if (t < nb) bsum[t] = (t > 0) ? s[t - 1] : 0;
}

// scan pass 3: add block offsets; also init scatter cursor
__global__ void scan3(int* __restrict__ start, int* __restrict__ cursor,
                      const int* __restrict__ bsum, int n) {
    int i = blockIdx.x * blockDim.x + threadIdx.x;
    if (i >= n) return;
    int v = start[i] + bsum[i >> 10];
    start[i] = v;
    cursor[i] = v;
}

__global__ void scatter_csr(const int* __restrict__ row, const int* __restrict__ col,
                            const float* __restrict__ val, int* __restrict__ cursor,
                            int2* __restrict__ edges, int nnz) {
    int i = blockIdx.x * blockDim.x + threadIdx.x;
    if (i >= nnz) return;
    int r = row[i];
    int p = atomicAdd(&cursor[r], 1);
    edges[p] = make_int2(col[i], __float_as_int(val[i]));
}

// ---------------- dense projection: z[n,16] = leaky(x[n,ldx]) @ T[f,15] ----

__global__ void dense_proj(const float* __restrict__ x, int ldx, int f, int fl,
                           const float* __restrict__ T, int n, float* __restrict__ z) {
    extern __shared__ float Tl[];  // fl * CONV, rows >= f zeroed
    for (int i = threadIdx.x; i < fl * CONV; i += blockDim.x) {
        int k = i / CONV, j = i - k * CONV;
        Tl[i] = (k < f) ? T[k * CONV + j] : 0.f;
    }
    __syncthreads();
    int i = blockIdx.x * blockDim.x + threadIdx.x;
    if (i >= n) return;
    const float* xr = x + (size_t)i * ldx;
    float acc[CONV];
#pragma unroll
    for (int j = 0; j < CONV; ++j) acc[j] = 0.f;
    for (int k = 0; k < fl; k += 4) {
        float4 xv = *reinterpret_cast<const float4*>(xr + k);
        float a0 = leaky(xv.x), a1 = leaky(xv.y), a2 = leaky(xv.z), a3 = leaky(xv.w);
        const float* T0 = Tl + k * CONV;
#pragma unroll
        for (int j = 0; j < CONV; ++j)
            acc[j] = fmaf(a0, T0[j], fmaf(a1, T0[CONV + j],
                     fmaf(a2, T0[2 * CONV + j], fmaf(a3, T0[3 * CONV + j], acc[j]))));
    }
    float* zr = z + (size_t)i * PADW;
#pragma unroll
    for (int j = 0; j < CONV; ++j) zr[j] = acc[j];
    zr[CONV] = 0.f;
}

// ---------------- gather SpMM: h[r,:] = sum_e val * z[col,:] --------------

__global__ void spmm_gather(const int* __restrict__ start, const int* __restrict__ counts,
                            const int2* __restrict__ edges, const float* __restrict__ z,
                            float* __restrict__ h, int n) {
    int tid = blockIdx.x * blockDim.x + threadIdx.x;
    int r = tid >> 4;
    int j = tid & 15;
    if (r >= n) return;
    int beg = start[r];
    int cnt = counts[r];
    float acc = 0.f;
    for (int e = 0; e < cnt; ++e) {
        int2 ed = edges[beg + e];
        acc = fmaf(__int_as_float(ed.y), z[ed.x * PADW + j], acc);
    }
    h[tid] = acc;   // tid == r*16+j; j==15 pad stays 0 (z pad col is 0)
}

// ---------------- pool: pooled[g,:] += partial segment sums ---------------

__global__ void pool_seg(const float* __restrict__ s3, const int* __restrict__ batch,
                         int n, float* __restrict__ pooled) {
    int g   = blockIdx.x >> 3;      // graph id
    int sub = blockIdx.x & (PSPLIT - 1);
    int lo = 0, hi = n;
    while (lo < hi) { int m = (lo + hi) >> 1; if (batch[m] < g) lo = m + 1; else hi = m; }
    int beg = lo;
    hi = n;
    while (lo < hi) { int m = (lo + hi) >> 1; if (batch[m] <= g) lo = m + 1; else hi = m; }
    int end = lo;
    int j  = threadIdx.x & 15;
    int rg = threadIdx.x >> 4;      // 0..15 row-groups in this block
    float acc = 0.f;
    for (int r = beg + sub * 16 + rg; r < end; r += 16 * PSPLIT)
        acc += s3[r * PADW + j];
    __shared__ float red[256];
    red[threadIdx.x] = acc;
    __syncthreads();
    for (int off = 128; off >= 16; off >>= 1) {
        if (threadIdx.x < off) red[threadIdx.x] += red[threadIdx.x + off];
        __syncthreads();
    }
    if (threadIdx.x < 16) atomicAdd(&pooled[g * PADW + threadIdx.x], red[threadIdx.x]);
}

// ---------------- finalize ------------------------------------------------

__global__ void finalize(const float* __restrict__ pooled,   // [3][NG*PADW]
                         const int* __restrict__ b0, int n0,
                         const int* __restrict__ b1, int n1,
                         const int* __restrict__ b2, int n2,
                         const float* __restrict__ t30, const float* __restrict__ t31,
                         const float* __restrict__ t32,
                         const float* __restrict__ W, const float* __restrict__ bias,
                         float* __restrict__ out) {
    int g = threadIdx.x;
    if (g >= NG) return;
    const int*   Bs[3]  = {b0, b1, b2};
    int          ns[3]  = {n0, n1, n2};
    const float* T3s[3] = {t30, t31, t32};
    float acc[OUTW];
#pragma unroll
    for (int o = 0; o < OUTW; ++o) acc[o] = 0.f;
    for (int l = 0; l < 3; ++l) {
        const int* B = Bs[l];
        int n = ns[l];
        int lo = 0, hi = n;
        while (lo < hi) { int m = (lo + hi) >> 1; if (B[m] < g) lo = m + 1; else hi = m; }
        int startg = lo;
        lo = 0; hi = n;
        while (lo < hi) { int m = (lo + hi) >> 1; if (B[m] <= g) lo = m + 1; else hi = m; }
        float c = fmaxf((float)(lo - startg), 1.f);
        float invc = 1.f / c;
        const float* P  = pooled + (size_t)l * NG * PADW + (size_t)g * PADW;
        const float* T3 = T3s[l];
#pragma unroll
        for (int o = 0; o < OUTW; ++o) {
            float s = 0.f;
            for (int k = 0; k < CONV; ++k) s = fmaf(P[k], T3[k * OUTW + o], s);
            acc[o] += s * invc;
        }
    }
    float logits[OUTW];
    float mx = -1e30f;
#pragma unroll
    for (int i = 0; i < OUTW; ++i) {
        float s = bias[i];
        for (int j = 0; j < OUTW; ++j) s = fmaf(acc[j], W[i * OUTW + j], s);
        logits[i] = s;
        mx = fmaxf(mx, s);
    }
    float denom = 0.f;
#pragma unroll
    for (int i = 0; i < OUTW; ++i) { logits[i] = expf(logits[i] - mx); denom += logits[i]; }
    float inv = 1.f / denom;
#pragma unroll
    for (int i = 0; i < OUTW; ++i) out[(size_t)g * OUTW + i] = logits[i] * inv;
}

// ---------------- host ----------------------------------------------------

extern "C" void kernel_launch(void* const* d_in, const int* in_sizes, int n_in,
                              void* d_out, int out_size, void* d_ws, size_t ws_size,
                              hipStream_t stream) {
    const float* x[3]    = {(const float*)d_in[0], (const float*)d_in[1], (const float*)d_in[2]};
    const int*   row[3]  = {(const int*)d_in[3], (const int*)d_in[6], (const int*)d_in[9]};
    const int*   colv[3] = {(const int*)d_in[4], (const int*)d_in[7], (const int*)d_in[10]};
    const float* val[3]  = {(const float*)d_in[5], (const float*)d_in[8], (const float*)d_in[11]};
    const int*   bat[3]  = {(const int*)d_in[12], (const int*)d_in[13], (const int*)d_in[14]};
    const float* t1[3]   = {(const float*)d_in[15], (const float*)d_in[18], (const float*)d_in[21]};
    const float* t2[3]   = {(const float*)d_in[16], (const float*)d_in[19], (const float*)d_in[22]};
    const float* t3[3]   = {(const float*)d_in[17], (const float*)d_in[20], (const float*)d_in[23]};
    const float* W       = (const float*)d_in[24];
    const float* bias    = (const float*)d_in[25];

    int n[3] = {in_sizes[12], in_sizes[13], in_sizes[14]};
    int f[3] = {in_sizes[0] / n[0], in_sizes[1] / n[1], in_sizes[2] / n[2]};
    int nnz[3] = {in_sizes[3], in_sizes[6], in_sizes[9]};

    int maxn = n[0];
    if (n[1] > maxn) maxn = n[1];
    if (n[2] > maxn) maxn = n[2];

    float* bufA   = (float*)d_ws;                          // [maxn,16]
    float* bufB   = bufA + (size_t)maxn * PADW;            // [maxn,16]
    float* pooled = bufB + (size_t)maxn * PADW;            // [3][NG*16]
    int*   counts = (int*)(pooled + 3 * NG * PADW);        // [maxn]
    int*   startA = counts + maxn;                         // [maxn]
    int*   cursor = startA + maxn;                         // [maxn]
    int*   bsum   = cursor + maxn;                         // [1024]
    int2*  edges  = (int2*)(bsum + 1024);                  // [max nnz]

    (void)hipMemsetAsync(pooled, 0, 3 * NG * PADW * sizeof(float), stream);

    for (int l = 0; l < 3; ++l) {
        int nl = n[l], fl = f[l], ml = nnz[l];
        int nbN = (nl + 255) / 256;
        int nbE = (ml + 255) / 256;
        int nbS = (nl + 1023) / 1024;
        int nbG = (nl * PADW + 255) / 256;

        // ---- CSR build ----
        (void)hipMemsetAsync(counts, 0, (size_t)nl * sizeof(int), stream);
        hist_rows<<<nbE, 256, 0, stream>>>(row[l], counts, ml);
        scan1<<<nbS, 256, 0, stream>>>(counts, startA, bsum, nl);
        scan2<<<1, 512, 0, stream>>>(bsum, nbS);
        scan3<<<nbN, 256, 0, stream>>>(startA, cursor, bsum, nl);
        scatter_csr<<<nbE, 256, 0, stream>>>(row[l], colv[l], val[l], cursor, edges, ml);

        // ---- z1 = leaky(x) @ T1 ; h1 = A z1 ----
        dense_proj<<<nbN, 256, fl * CONV * sizeof(float), stream>>>(
            x[l], fl, fl, fl, t1[l], nl, bufA);
        spmm_gather<<<nbG, 256, 0, stream>>>(startA, counts, edges, bufA, bufB, nl);

        // ---- z2 = leaky(h1) @ T2 ; h2 = A z2 ----
        dense_proj<<<nbN, 256, PADW * CONV * sizeof(float), stream>>>(
            bufB, PADW, CONV, PADW, t2[l], nl, bufA);
        spmm_gather<<<nbG, 256, 0, stream>>>(startA, counts, edges, bufA, bufB, nl);

        // ---- s3 = A h2 (no leaky, T3 deferred) ----
        spmm_gather<<<nbG, 256, 0, stream>>>(startA, counts, edges, bufB, bufA, nl);

        // ---- pooled_l += segment partial sums (sorted batch) ----
        pool_seg<<<NG * PSPLIT, 256, 0, stream>>>(bufA, bat[l], nl,
                                                  pooled + (size_t)l * NG * PADW);
    }

    finalize<<<1, 64, 0, stream>>>(pooled,
                                   bat[0], n[0], bat[1], n[1], bat[2], n[2],
                                   t3[0], t3[1], t3[2], W, bias, (float*)d_out);
}